// Round 3
// baseline (575.530 us; speedup 1.0000x reference)
//
#include <hip/hip_runtime.h>

#define S_     264
#define BL_    256
#define TWO_S  528
#define TWO_BL 512
#define B_     512
#define V_     128
#define NQ     392   // S + V
#define Z_     1024
#define N2_    1056  // S*4
#define NTOT   1184  // N2 + V

// ---------------------------------------------------------------------------
// Kernel 1: one block per (batch, psi). Register-resident single pass with
// fused accumulator u = coefY*t_y + coefS*t_sql and 2-deep prefetch.
// Also copies x_mag into out0 (first half) from psi==0 blocks.
// ---------------------------------------------------------------------------
__global__ __launch_bounds__(256, 4) void k_psi(
    const float* __restrict__ x_mag, const float* __restrict__ x_phase,
    const float* __restrict__ y_e, const float* __restrict__ y_o,
    const float* __restrict__ Psi_e, const float* __restrict__ Psi_o,
    const float* __restrict__ d1, const float* __restrict__ d2,
    const float* __restrict__ d4,
    float* __restrict__ contrib, float* __restrict__ out0)
{
    const int tid = threadIdx.x;
    const int b   = blockIdx.x >> 1;
    const int psi = blockIdx.x & 1;
    const float* Psi = psi ? Psi_o : Psi_e;
    const float* yv  = psi ? y_o  : y_e;
    const float coefY = psi ? -d2[0] : -d1[0];
    const float coefS = psi ?  d4[0] :  d2[0];

    __shared__ float4 xs4s[132];                 // x = [mag*c, mag*s]
    __shared__ float  cs[S_], sn[S_];
    __shared__ float  gys[BL_];                  // coefY * y
    __shared__ float4 redU4[4][132];

    float* xs = (float*)xs4s;

    for (int s = tid; s < S_; s += 256) {
        float mag = x_mag[(size_t)b * S_ + s];
        float ph  = x_phase[(size_t)b * S_ + s];
        float c = cosf(ph), si = sinf(ph);
        cs[s] = c; sn[s] = si;
        xs[s]      = mag * c;
        xs[S_ + s] = mag * si;
        if (psi == 0) out0[(size_t)b * S_ + s] = mag;
    }
    gys[tid] = coefY * yv[(size_t)b * BL_ + tid];
    __syncthreads();

    const int wave = tid >> 6, lane = tid & 63;
    const float4 f4z = {0.f, 0.f, 0.f, 0.f};

    float4 x0 = xs4s[lane];
    float4 x1 = xs4s[lane + 64];
    float4 x2 = (lane < 4) ? xs4s[lane + 128] : f4z;

    float4 u0 = f4z, u1 = f4z, u2 = f4z;

    const float4* Pg = (const float4*)(Psi + (size_t)b * TWO_BL * TWO_S);

#define LOADF(PP, L0, L1, L2, H0, H1, H2) {                         \
        const float4* rl_ = Pg + (size_t)(PP) * 132;                \
        const float4* rh_ = rl_ + (size_t)BL_ * 132;                \
        L0 = rl_[lane]; L1 = rl_[lane + 64];                        \
        H0 = rh_[lane]; H1 = rh_[lane + 64];                        \
        if (lane < 4) { L2 = rl_[lane + 128]; H2 = rh_[lane + 128]; } \
        else          { L2 = f4z; H2 = f4z; }                       \
    }

#define COMPUTE(L0, L1, L2, H0, H1, H2, PIDX) {                     \
        float a  = L0.x*x0.x + L0.y*x0.y + L0.z*x0.z + L0.w*x0.w    \
                 + L1.x*x1.x + L1.y*x1.y + L1.z*x1.z + L1.w*x1.w    \
                 + L2.x*x2.x + L2.y*x2.y + L2.z*x2.z + L2.w*x2.w;   \
        float bb = H0.x*x0.x + H0.y*x0.y + H0.z*x0.z + H0.w*x0.w    \
                 + H1.x*x1.x + H1.y*x1.y + H1.z*x1.z + H1.w*x1.w    \
                 + H2.x*x2.x + H2.y*x2.y + H2.z*x2.z + H2.w*x2.w;   \
        _Pragma("unroll")                                           \
        for (int off_ = 32; off_; off_ >>= 1) {                     \
            a  += __shfl_xor(a, off_);                              \
            bb += __shfl_xor(bb, off_);                             \
        }                                                           \
        float g  = gys[PIDX] + coefS * (a * a + bb * bb);           \
        float wl = a * g, wh = bb * g;                              \
        u0.x += L0.x*wl + H0.x*wh;  u0.y += L0.y*wl + H0.y*wh;      \
        u0.z += L0.z*wl + H0.z*wh;  u0.w += L0.w*wl + H0.w*wh;      \
        u1.x += L1.x*wl + H1.x*wh;  u1.y += L1.y*wl + H1.y*wh;      \
        u1.z += L1.z*wl + H1.z*wh;  u1.w += L1.w*wl + H1.w*wh;      \
        u2.x += L2.x*wl + H2.x*wh;  u2.y += L2.y*wl + H2.y*wh;      \
        u2.z += L2.z*wl + H2.z*wh;  u2.w += L2.w*wl + H2.w*wh;      \
    }

    // pairs for this wave: wave + 4*j, j = 0..63; unroll-2, 2-deep prefetch
    float4 al0, al1, al2, ah0, ah1, ah2;
    float4 bl0, bl1, bl2, bh0, bh1, bh2;
    LOADF(wave,     al0, al1, al2, ah0, ah1, ah2);
    LOADF(wave + 4, bl0, bl1, bl2, bh0, bh1, bh2);

    for (int j = 0; j < 64; j += 2) {
        const int pA = wave + 4 * j;
        const int pC = (j + 2 < 64) ? pA + 8  : 0;
        const int pD = (j + 3 < 64) ? pA + 12 : 0;
        float4 cl0, cl1, cl2, ch0, ch1, ch2;
        LOADF(pC, cl0, cl1, cl2, ch0, ch1, ch2);
        COMPUTE(al0, al1, al2, ah0, ah1, ah2, pA);
        float4 dl0, dl1, dl2, dh0, dh1, dh2;
        LOADF(pD, dl0, dl1, dl2, dh0, dh1, dh2);
        COMPUTE(bl0, bl1, bl2, bh0, bh1, bh2, pA + 4);
        al0 = cl0; al1 = cl1; al2 = cl2; ah0 = ch0; ah1 = ch1; ah2 = ch2;
        bl0 = dl0; bl1 = dl1; bl2 = dl2; bh0 = dh0; bh1 = dh1; bh2 = dh2;
    }
#undef LOADF
#undef COMPUTE

    redU4[wave][lane]      = u0;
    redU4[wave][lane + 64] = u1;
    if (lane < 4) redU4[wave][lane + 128] = u2;
    __syncthreads();

    const float* redU = (const float*)redU4;
    float* outp = contrib + (size_t)(b * 2 + psi) * S_;
    for (int s = tid; s < S_; s += 256) {
        float ul = 0.f, uh = 0.f;
        #pragma unroll
        for (int w = 0; w < 4; ++w) {
            ul += redU[w * TWO_S + s];
            uh += redU[w * TWO_S + S_ + s];
        }
        outp[s] = cs[s] * ul + sn[s] * uh;
    }
}

// ---------------------------------------------------------------------------
// GEMM1 (fused cat): z = relu([q, v] @ W1^T + b1), q = x_mag + contrib_e+o.
// Tile 32x64, thread 2x4, K-chunk 32.
// ---------------------------------------------------------------------------
__global__ __launch_bounds__(256) void k_gemm1(
    const float* __restrict__ x_mag, const float* __restrict__ contrib,
    const float* __restrict__ v, const float* __restrict__ W1,
    const float* __restrict__ b1, float* __restrict__ z)
{
    const int tid = threadIdx.x;
    const int m0  = blockIdx.x * 32;
    const int n0  = blockIdx.y * 64;
    const int trow = (tid >> 4) * 2;        // 0..30
    const int tcol = (tid & 15) * 4;        // 0..60

    __shared__ float As[32][36];   // As[k][r]
    __shared__ float Ws[32][68];   // Ws[k][c]

    float acc[2][4] = {};

    const int krA  = tid >> 3;        // 0..31
    const int kkA  = (tid & 7) * 4;   // 0..28

    for (int kc = 0; kc < NQ; kc += 32) {
        // ---- stage A (cat built on the fly)
        {
            const int arow = m0 + krA;
            const int gk = kc + kkA;
            float4 vv = {0.f, 0.f, 0.f, 0.f};
            if (gk < S_) {
                float4 xm = *(const float4*)&x_mag[(size_t)arow * S_ + gk];
                float4 ce = *(const float4*)&contrib[(size_t)(arow * 2) * S_ + gk];
                float4 co = *(const float4*)&contrib[(size_t)(arow * 2 + 1) * S_ + gk];
                vv.x = xm.x + ce.x + co.x; vv.y = xm.y + ce.y + co.y;
                vv.z = xm.z + ce.z + co.z; vv.w = xm.w + ce.w + co.w;
            } else if (gk < NQ) {
                vv = *(const float4*)&v[(size_t)arow * V_ + (gk - S_)];
            }
            As[kkA + 0][krA] = vv.x; As[kkA + 1][krA] = vv.y;
            As[kkA + 2][krA] = vv.z; As[kkA + 3][krA] = vv.w;
        }
        // ---- stage W
        for (int i = tid; i < 512; i += 256) {
            const int r  = i >> 3;
            const int j4 = (i & 7) * 4;
            const int gk = kc + j4;
            float4 vv = {0.f, 0.f, 0.f, 0.f};
            if (gk < NQ)
                vv = *(const float4*)&W1[(size_t)(n0 + r) * NQ + gk];
            Ws[j4 + 0][r] = vv.x; Ws[j4 + 1][r] = vv.y;
            Ws[j4 + 2][r] = vv.z; Ws[j4 + 3][r] = vv.w;
        }
        __syncthreads();

        #pragma unroll
        for (int k = 0; k < 32; ++k) {
            float2 a2 = *(const float2*)&As[k][trow];
            float4 w4 = *(const float4*)&Ws[k][tcol];
            acc[0][0] += a2.x * w4.x; acc[0][1] += a2.x * w4.y;
            acc[0][2] += a2.x * w4.z; acc[0][3] += a2.x * w4.w;
            acc[1][0] += a2.y * w4.x; acc[1][1] += a2.y * w4.y;
            acc[1][2] += a2.y * w4.z; acc[1][3] += a2.y * w4.w;
        }
        __syncthreads();
    }

    #pragma unroll
    for (int i = 0; i < 2; ++i) {
        const int row = m0 + trow + i;
        const int col = n0 + tcol;
        float4 r;
        r.x = fmaxf(acc[i][0] + b1[col + 0], 0.f);
        r.y = fmaxf(acc[i][1] + b1[col + 1], 0.f);
        r.z = fmaxf(acc[i][2] + b1[col + 2], 0.f);
        r.w = fmaxf(acc[i][3] + b1[col + 3], 0.f);
        *(float4*)&z[(size_t)row * Z_ + col] = r;
    }
}

// ---------------------------------------------------------------------------
// GEMM23 (fused): [out_oh | out_v] = z @ [W2;W3]^T + [b2;b3] + [oh | v]
// plus fused softmax-MAPP epilogue writing out0's second half.
// Tile 32x64 over virtual N = 1184. K = 1024, K-chunk 32.
// ---------------------------------------------------------------------------
__global__ __launch_bounds__(256) void k_gemm23(
    const float* __restrict__ z,
    const float* __restrict__ W2, const float* __restrict__ b2,
    const float* __restrict__ oh,
    const float* __restrict__ W3, const float* __restrict__ b3,
    const float* __restrict__ v,
    float* __restrict__ out_oh, float* __restrict__ out_v,
    float* __restrict__ out0)
{
    const int tid = threadIdx.x;
    const int m0  = blockIdx.x * 32;
    const int n0  = blockIdx.y * 64;
    const int trow = (tid >> 4) * 2;
    const int tcol = (tid & 15) * 4;

    __shared__ float As[32][36];
    __shared__ float Ws[32][68];

    float acc[2][4] = {};

    const int krA = tid >> 3;
    const int kkA = (tid & 7) * 4;

    for (int kc = 0; kc < Z_; kc += 32) {
        {
            float4 vv = *(const float4*)&z[(size_t)(m0 + krA) * Z_ + kc + kkA];
            As[kkA + 0][krA] = vv.x; As[kkA + 1][krA] = vv.y;
            As[kkA + 2][krA] = vv.z; As[kkA + 3][krA] = vv.w;
        }
        for (int i = tid; i < 512; i += 256) {
            const int r  = i >> 3;
            const int j4 = (i & 7) * 4;
            const int wrow = n0 + r;
            float4 vv = {0.f, 0.f, 0.f, 0.f};
            if (wrow < NTOT) {
                const float* wp = (wrow < N2_)
                    ? (W2 + (size_t)wrow * Z_)
                    : (W3 + (size_t)(wrow - N2_) * Z_);
                vv = *(const float4*)&wp[kc + j4];
            }
            Ws[j4 + 0][r] = vv.x; Ws[j4 + 1][r] = vv.y;
            Ws[j4 + 2][r] = vv.z; Ws[j4 + 3][r] = vv.w;
        }
        __syncthreads();

        #pragma unroll
        for (int k = 0; k < 32; ++k) {
            float2 a2 = *(const float2*)&As[k][trow];
            float4 w4 = *(const float4*)&Ws[k][tcol];
            acc[0][0] += a2.x * w4.x; acc[0][1] += a2.x * w4.y;
            acc[0][2] += a2.x * w4.z; acc[0][3] += a2.x * w4.w;
            acc[1][0] += a2.y * w4.x; acc[1][1] += a2.y * w4.y;
            acc[1][2] += a2.y * w4.z; acc[1][3] += a2.y * w4.w;
        }
        __syncthreads();
    }

    #pragma unroll
    for (int i = 0; i < 2; ++i) {
        const int row = m0 + trow + i;
        const int col = n0 + tcol;
        if (col < N2_) {
            float4 ad = *(const float4*)&oh[(size_t)row * N2_ + col];
            float4 r;
            r.x = acc[i][0] + b2[col + 0] + ad.x;
            r.y = acc[i][1] + b2[col + 1] + ad.y;
            r.z = acc[i][2] + b2[col + 2] + ad.z;
            r.w = acc[i][3] + b2[col + 3] + ad.w;
            *(float4*)&out_oh[(size_t)row * N2_ + col] = r;
            // fused softmax(r) @ MAPP
            float m  = fmaxf(fmaxf(r.x, r.y), fmaxf(r.z, r.w));
            float e0 = expf(r.x - m), e1 = expf(r.y - m);
            float e2 = expf(r.z - m), e3 = expf(r.w - m);
            float sum = e0 + e1 + e2 + e3;
            float sym = (0.5f * e0 + 1.0f * e1 + 1.5f * e2 + 2.0f * e3) / sum;
            out0[(size_t)B_ * S_ + (size_t)row * S_ + (col >> 2)] = sym;
        } else if (col < NTOT) {
            const int c3 = col - N2_;
            float4 ad = *(const float4*)&v[(size_t)row * V_ + c3];
            float4 r;
            r.x = acc[i][0] + b3[c3 + 0] + ad.x;
            r.y = acc[i][1] + b3[c3 + 1] + ad.y;
            r.z = acc[i][2] + b3[c3 + 2] + ad.z;
            r.w = acc[i][3] + b3[c3 + 3] + ad.w;
            *(float4*)&out_v[(size_t)row * V_ + c3] = r;
        }
    }
}

// ---------------------------------------------------------------------------
extern "C" void kernel_launch(void* const* d_in, const int* in_sizes, int n_in,
                              void* d_out, int out_size, void* d_ws, size_t ws_size,
                              hipStream_t stream)
{
    const float* x_mag    = (const float*)d_in[1];
    const float* x_mag_oh = (const float*)d_in[2];
    const float* v        = (const float*)d_in[3];
    const float* x_phase  = (const float*)d_in[4];
    const float* y_e      = (const float*)d_in[5];
    const float* y_o      = (const float*)d_in[6];
    const float* Psi_e    = (const float*)d_in[7];
    const float* Psi_o    = (const float*)d_in[8];
    const float* W1       = (const float*)d_in[9];
    const float* b1       = (const float*)d_in[10];
    const float* W2       = (const float*)d_in[11];
    const float* b2       = (const float*)d_in[12];
    const float* W3       = (const float*)d_in[13];
    const float* b3       = (const float*)d_in[14];
    const float* d1       = (const float*)d_in[15];
    const float* d2       = (const float*)d_in[16];
    const float* d4       = (const float*)d_in[18];   // d3 (d_in[17]) unused

    float* ws      = (float*)d_ws;
    float* contrib = ws;                         // 1024 * 264
    float* z       = contrib + 1024 * S_;        // 512 * 1024

    float* out0   = (float*)d_out;               // 2*512*264 (x_mag_new)
    float* out_oh = out0 + 2 * B_ * S_;          // 512*1056  (x_mag_oh_new)
    float* out_v  = out_oh + B_ * N2_;           // 512*128   (v_new)

    k_psi<<<dim3(B_ * 2), dim3(256), 0, stream>>>(
        x_mag, x_phase, y_e, y_o, Psi_e, Psi_o, d1, d2, d4, contrib, out0);

    k_gemm1<<<dim3(16, 16), dim3(256), 0, stream>>>(
        x_mag, contrib, v, W1, b1, z);

    k_gemm23<<<dim3(16, 19), dim3(256), 0, stream>>>(
        z, W2, b2, x_mag_oh, W3, b3, v, out_oh, out_v, out0);
}

// Round 4
// 299.600 us; speedup vs baseline: 1.9210x; 1.9210x over previous
//
#include <hip/hip_runtime.h>
#include <stdint.h>

#define S_     264
#define BL_    256
#define TWO_S  528
#define TWO_BL 512
#define B_     512
#define V_     128
#define NQ     392   // S + V
#define Z_     1024
#define N2_    1056  // S*4
#define NTOT   1184  // N2 + V

#define CHUNK_F4 1056   // per chunk: 4 lo rows + 4 hi rows, each 132 float4
#define NCHUNK   64

// async global->LDS, 16 bytes per lane (dest = wave-uniform base + lane*16,
// which matches our linear layout exactly)
__device__ __forceinline__ void gload_lds16(const void* g, void* l) {
    __builtin_amdgcn_global_load_lds(
        (const __attribute__((address_space(1))) uint32_t*)g,
        (__attribute__((address_space(3))) uint32_t*)l, 16, 0, 0);
}

// stage 4 lo rows (m0..m0+3) + 4 hi rows (m0+256..m0+259), 1056 float4 total,
// into dst (linear). 4 full rounds of 256 lanes + 32-lane tail.
__device__ __forceinline__ void stage_chunk(const float4* Pg, int chunk,
                                            float4* dst, int tid) {
    const float4* lo = Pg + (size_t)(chunk * 4) * 132;
    const float4* hi = Pg + (size_t)(chunk * 4 + BL_) * 132;
    #pragma unroll
    for (int r = 0; r < 4; ++r) {
        const int i = r * 256 + tid;
        const float4* g = (i < 528) ? (lo + i) : (hi + (i - 528));
        gload_lds16((const void*)g, (void*)(dst + i));
    }
    if (tid < 32) {
        const int i = 1024 + tid;
        gload_lds16((const void*)(hi + (i - 528)), (void*)(dst + i));
    }
}

// ---------------------------------------------------------------------------
// Kernel 1: one block per (batch, psi). LDS double-buffered single pass.
// Per chunk: wave w owns row-pair (chunk*4+w, +256). Dots via b128 LDS reads
// + butterfly shfl; fused accumulator u = coefY*t_y + coefS*t_sql.
// Also copies x_mag into out0 (first half) from psi==0 blocks.
// ---------------------------------------------------------------------------
__global__ __launch_bounds__(256, 4) void k_psi(
    const float* __restrict__ x_mag, const float* __restrict__ x_phase,
    const float* __restrict__ y_e, const float* __restrict__ y_o,
    const float* __restrict__ Psi_e, const float* __restrict__ Psi_o,
    const float* __restrict__ d1, const float* __restrict__ d2,
    const float* __restrict__ d4,
    float* __restrict__ contrib, float* __restrict__ out0)
{
    const int tid = threadIdx.x;
    const int b   = blockIdx.x >> 1;
    const int psi = blockIdx.x & 1;
    const float* Psi = psi ? Psi_o : Psi_e;
    const float* yv  = psi ? y_o  : y_e;
    const float coefY = psi ? -d2[0] : -d1[0];
    const float coefS = psi ?  d4[0] :  d2[0];

    __shared__ float4 bufA[CHUNK_F4];
    __shared__ float4 bufB[CHUNK_F4];
    __shared__ float4 xs4[132];          // x = [mag*c, mag*s], 528 floats
    __shared__ float  cs[S_], sn[S_];
    __shared__ float  gys[BL_];          // coefY * y

    float* xs = (float*)xs4;

    for (int s = tid; s < S_; s += 256) {
        float mag = x_mag[(size_t)b * S_ + s];
        float ph  = x_phase[(size_t)b * S_ + s];
        float c = cosf(ph), si = sinf(ph);
        cs[s] = c; sn[s] = si;
        xs[s]      = mag * c;
        xs[S_ + s] = mag * si;
        if (psi == 0) out0[(size_t)b * S_ + s] = mag;
    }
    gys[tid] = coefY * yv[(size_t)b * BL_ + tid];

    const float4* Pg = (const float4*)(Psi + (size_t)b * TWO_BL * TWO_S);

    stage_chunk(Pg, 0, bufA, tid);
    __syncthreads();                     // drains stage0 + prologue LDS writes

    const int wave = tid >> 6, lane = tid & 63;
    const float4 f4z = {0.f, 0.f, 0.f, 0.f};

    float4 x0 = xs4[lane];
    float4 x1 = xs4[lane + 64];
    float4 x2 = (lane < 4) ? xs4[lane + 128] : f4z;

    float4 u0 = f4z, u1 = f4z, u2 = f4z;

    for (int c = 0; c < NCHUNK; ++c) {
        float4* cur = (c & 1) ? bufB : bufA;
        float4* nxt = (c & 1) ? bufA : bufB;
        if (c + 1 < NCHUNK) stage_chunk(Pg, c + 1, nxt, tid);

        // compute pair (c*4 + wave): lo at cur+wave*132, hi at +528
        const float4* bl = cur + wave * 132;
        const float4* bh = bl + 528;
        float4 l0 = bl[lane], l1 = bl[lane + 64];
        float4 h0 = bh[lane], h1 = bh[lane + 64];
        float4 l2 = f4z, h2 = f4z;
        if (lane < 4) { l2 = bl[lane + 128]; h2 = bh[lane + 128]; }

        float a  = l0.x*x0.x + l0.y*x0.y + l0.z*x0.z + l0.w*x0.w
                 + l1.x*x1.x + l1.y*x1.y + l1.z*x1.z + l1.w*x1.w
                 + l2.x*x2.x + l2.y*x2.y + l2.z*x2.z + l2.w*x2.w;
        float bb = h0.x*x0.x + h0.y*x0.y + h0.z*x0.z + h0.w*x0.w
                 + h1.x*x1.x + h1.y*x1.y + h1.z*x1.z + h1.w*x1.w
                 + h2.x*x2.x + h2.y*x2.y + h2.z*x2.z + h2.w*x2.w;
        #pragma unroll
        for (int off = 32; off; off >>= 1) {
            a  += __shfl_xor(a, off);
            bb += __shfl_xor(bb, off);
        }

        const float g  = gys[c * 4 + wave] + coefS * (a * a + bb * bb);
        const float wl = a * g, wh = bb * g;

        u0.x += l0.x*wl + h0.x*wh;  u0.y += l0.y*wl + h0.y*wh;
        u0.z += l0.z*wl + h0.z*wh;  u0.w += l0.w*wl + h0.w*wh;
        u1.x += l1.x*wl + h1.x*wh;  u1.y += l1.y*wl + h1.y*wh;
        u1.z += l1.z*wl + h1.z*wh;  u1.w += l1.w*wl + h1.w*wh;
        u2.x += l2.x*wl + h2.x*wh;  u2.y += l2.y*wl + h2.y*wh;
        u2.z += l2.z*wl + h2.z*wh;  u2.w += l2.w*wl + h2.w*wh;

        __syncthreads();                 // stage(c+1) drained; cur free next
    }

    // per-wave partials -> reuse bufA as reduction scratch (528 floats/wave)
    float4* redU4 = bufA;
    redU4[wave * 132 + lane]      = u0;
    redU4[wave * 132 + 64 + lane] = u1;
    if (lane < 4) redU4[wave * 132 + 128 + lane] = u2;
    __syncthreads();

    const float* redU = (const float*)bufA;
    float* outp = contrib + (size_t)(b * 2 + psi) * S_;
    for (int s = tid; s < S_; s += 256) {
        float ul = redU[0*TWO_S + s]       + redU[1*TWO_S + s]
                 + redU[2*TWO_S + s]       + redU[3*TWO_S + s];
        float uh = redU[0*TWO_S + S_ + s]  + redU[1*TWO_S + S_ + s]
                 + redU[2*TWO_S + S_ + s]  + redU[3*TWO_S + S_ + s];
        outp[s] = cs[s] * ul + sn[s] * uh;
    }
}

// ---------------------------------------------------------------------------
// GEMM1 (fused cat): z = relu([q, v] @ W1^T + b1), q = x_mag + contrib_e+o.
// Tile 32x64, thread 2x4, K-chunk 32.
// ---------------------------------------------------------------------------
__global__ __launch_bounds__(256) void k_gemm1(
    const float* __restrict__ x_mag, const float* __restrict__ contrib,
    const float* __restrict__ v, const float* __restrict__ W1,
    const float* __restrict__ b1, float* __restrict__ z)
{
    const int tid = threadIdx.x;
    const int m0  = blockIdx.x * 32;
    const int n0  = blockIdx.y * 64;
    const int trow = (tid >> 4) * 2;        // 0..30
    const int tcol = (tid & 15) * 4;        // 0..60

    __shared__ float As[32][36];   // As[k][r]
    __shared__ float Ws[32][68];   // Ws[k][c]

    float acc[2][4] = {};

    const int krA  = tid >> 3;        // 0..31
    const int kkA  = (tid & 7) * 4;   // 0..28

    for (int kc = 0; kc < NQ; kc += 32) {
        {
            const int arow = m0 + krA;
            const int gk = kc + kkA;
            float4 vv = {0.f, 0.f, 0.f, 0.f};
            if (gk < S_) {
                float4 xm = *(const float4*)&x_mag[(size_t)arow * S_ + gk];
                float4 ce = *(const float4*)&contrib[(size_t)(arow * 2) * S_ + gk];
                float4 co = *(const float4*)&contrib[(size_t)(arow * 2 + 1) * S_ + gk];
                vv.x = xm.x + ce.x + co.x; vv.y = xm.y + ce.y + co.y;
                vv.z = xm.z + ce.z + co.z; vv.w = xm.w + ce.w + co.w;
            } else if (gk < NQ) {
                vv = *(const float4*)&v[(size_t)arow * V_ + (gk - S_)];
            }
            As[kkA + 0][krA] = vv.x; As[kkA + 1][krA] = vv.y;
            As[kkA + 2][krA] = vv.z; As[kkA + 3][krA] = vv.w;
        }
        for (int i = tid; i < 512; i += 256) {
            const int r  = i >> 3;
            const int j4 = (i & 7) * 4;
            const int gk = kc + j4;
            float4 vv = {0.f, 0.f, 0.f, 0.f};
            if (gk < NQ)
                vv = *(const float4*)&W1[(size_t)(n0 + r) * NQ + gk];
            Ws[j4 + 0][r] = vv.x; Ws[j4 + 1][r] = vv.y;
            Ws[j4 + 2][r] = vv.z; Ws[j4 + 3][r] = vv.w;
        }
        __syncthreads();

        #pragma unroll
        for (int k = 0; k < 32; ++k) {
            float2 a2 = *(const float2*)&As[k][trow];
            float4 w4 = *(const float4*)&Ws[k][tcol];
            acc[0][0] += a2.x * w4.x; acc[0][1] += a2.x * w4.y;
            acc[0][2] += a2.x * w4.z; acc[0][3] += a2.x * w4.w;
            acc[1][0] += a2.y * w4.x; acc[1][1] += a2.y * w4.y;
            acc[1][2] += a2.y * w4.z; acc[1][3] += a2.y * w4.w;
        }
        __syncthreads();
    }

    #pragma unroll
    for (int i = 0; i < 2; ++i) {
        const int row = m0 + trow + i;
        const int col = n0 + tcol;
        float4 r;
        r.x = fmaxf(acc[i][0] + b1[col + 0], 0.f);
        r.y = fmaxf(acc[i][1] + b1[col + 1], 0.f);
        r.z = fmaxf(acc[i][2] + b1[col + 2], 0.f);
        r.w = fmaxf(acc[i][3] + b1[col + 3], 0.f);
        *(float4*)&z[(size_t)row * Z_ + col] = r;
    }
}

// ---------------------------------------------------------------------------
// GEMM23 (fused): [out_oh | out_v] = z @ [W2;W3]^T + [b2;b3] + [oh | v]
// plus fused softmax-MAPP epilogue writing out0's second half.
// ---------------------------------------------------------------------------
__global__ __launch_bounds__(256) void k_gemm23(
    const float* __restrict__ z,
    const float* __restrict__ W2, const float* __restrict__ b2,
    const float* __restrict__ oh,
    const float* __restrict__ W3, const float* __restrict__ b3,
    const float* __restrict__ v,
    float* __restrict__ out_oh, float* __restrict__ out_v,
    float* __restrict__ out0)
{
    const int tid = threadIdx.x;
    const int m0  = blockIdx.x * 32;
    const int n0  = blockIdx.y * 64;
    const int trow = (tid >> 4) * 2;
    const int tcol = (tid & 15) * 4;

    __shared__ float As[32][36];
    __shared__ float Ws[32][68];

    float acc[2][4] = {};

    const int krA = tid >> 3;
    const int kkA = (tid & 7) * 4;

    for (int kc = 0; kc < Z_; kc += 32) {
        {
            float4 vv = *(const float4*)&z[(size_t)(m0 + krA) * Z_ + kc + kkA];
            As[kkA + 0][krA] = vv.x; As[kkA + 1][krA] = vv.y;
            As[kkA + 2][krA] = vv.z; As[kkA + 3][krA] = vv.w;
        }
        for (int i = tid; i < 512; i += 256) {
            const int r  = i >> 3;
            const int j4 = (i & 7) * 4;
            const int wrow = n0 + r;
            float4 vv = {0.f, 0.f, 0.f, 0.f};
            if (wrow < NTOT) {
                const float* wp = (wrow < N2_)
                    ? (W2 + (size_t)wrow * Z_)
                    : (W3 + (size_t)(wrow - N2_) * Z_);
                vv = *(const float4*)&wp[kc + j4];
            }
            Ws[j4 + 0][r] = vv.x; Ws[j4 + 1][r] = vv.y;
            Ws[j4 + 2][r] = vv.z; Ws[j4 + 3][r] = vv.w;
        }
        __syncthreads();

        #pragma unroll
        for (int k = 0; k < 32; ++k) {
            float2 a2 = *(const float2*)&As[k][trow];
            float4 w4 = *(const float4*)&Ws[k][tcol];
            acc[0][0] += a2.x * w4.x; acc[0][1] += a2.x * w4.y;
            acc[0][2] += a2.x * w4.z; acc[0][3] += a2.x * w4.w;
            acc[1][0] += a2.y * w4.x; acc[1][1] += a2.y * w4.y;
            acc[1][2] += a2.y * w4.z; acc[1][3] += a2.y * w4.w;
        }
        __syncthreads();
    }

    #pragma unroll
    for (int i = 0; i < 2; ++i) {
        const int row = m0 + trow + i;
        const int col = n0 + tcol;
        if (col < N2_) {
            float4 ad = *(const float4*)&oh[(size_t)row * N2_ + col];
            float4 r;
            r.x = acc[i][0] + b2[col + 0] + ad.x;
            r.y = acc[i][1] + b2[col + 1] + ad.y;
            r.z = acc[i][2] + b2[col + 2] + ad.z;
            r.w = acc[i][3] + b2[col + 3] + ad.w;
            *(float4*)&out_oh[(size_t)row * N2_ + col] = r;
            float m  = fmaxf(fmaxf(r.x, r.y), fmaxf(r.z, r.w));
            float e0 = expf(r.x - m), e1 = expf(r.y - m);
            float e2 = expf(r.z - m), e3 = expf(r.w - m);
            float sum = e0 + e1 + e2 + e3;
            float sym = (0.5f * e0 + 1.0f * e1 + 1.5f * e2 + 2.0f * e3) / sum;
            out0[(size_t)B_ * S_ + (size_t)row * S_ + (col >> 2)] = sym;
        } else if (col < NTOT) {
            const int c3 = col - N2_;
            float4 ad = *(const float4*)&v[(size_t)row * V_ + c3];
            float4 r;
            r.x = acc[i][0] + b3[c3 + 0] + ad.x;
            r.y = acc[i][1] + b3[c3 + 1] + ad.y;
            r.z = acc[i][2] + b3[c3 + 2] + ad.z;
            r.w = acc[i][3] + b3[c3 + 3] + ad.w;
            *(float4*)&out_v[(size_t)row * V_ + c3] = r;
        }
    }
}

// ---------------------------------------------------------------------------
extern "C" void kernel_launch(void* const* d_in, const int* in_sizes, int n_in,
                              void* d_out, int out_size, void* d_ws, size_t ws_size,
                              hipStream_t stream)
{
    const float* x_mag    = (const float*)d_in[1];
    const float* x_mag_oh = (const float*)d_in[2];
    const float* v        = (const float*)d_in[3];
    const float* x_phase  = (const float*)d_in[4];
    const float* y_e      = (const float*)d_in[5];
    const float* y_o      = (const float*)d_in[6];
    const float* Psi_e    = (const float*)d_in[7];
    const float* Psi_o    = (const float*)d_in[8];
    const float* W1       = (const float*)d_in[9];
    const float* b1       = (const float*)d_in[10];
    const float* W2       = (const float*)d_in[11];
    const float* b2       = (const float*)d_in[12];
    const float* W3       = (const float*)d_in[13];
    const float* b3       = (const float*)d_in[14];
    const float* d1       = (const float*)d_in[15];
    const float* d2       = (const float*)d_in[16];
    const float* d4       = (const float*)d_in[18];   // d3 (d_in[17]) unused

    float* ws      = (float*)d_ws;
    float* contrib = ws;                         // 1024 * 264
    float* z       = contrib + 1024 * S_;        // 512 * 1024

    float* out0   = (float*)d_out;               // 2*512*264 (x_mag_new)
    float* out_oh = out0 + 2 * B_ * S_;          // 512*1056  (x_mag_oh_new)
    float* out_v  = out_oh + B_ * N2_;           // 512*128   (v_new)

    k_psi<<<dim3(B_ * 2), dim3(256), 0, stream>>>(
        x_mag, x_phase, y_e, y_o, Psi_e, Psi_o, d1, d2, d4, contrib, out0);

    k_gemm1<<<dim3(16, 16), dim3(256), 0, stream>>>(
        x_mag, contrib, v, W1, b1, z);

    k_gemm23<<<dim3(16, 19), dim3(256), 0, stream>>>(
        z, W2, b2, x_mag_oh, W3, b3, v, out_oh, out_v, out0);
}